// Round 3
// baseline (274.496 us; speedup 1.0000x reference)
//
#include <hip/hip_runtime.h>
#include <stdint.h>

// ---------------- problem constants ----------------
#define BB 4
#define RR 4
#define NN 4096
#define MM 64
#define KK 3
#define KNN 12288           // KK*NN
#define BRR 16              // BB*RR
#define FF 512

typedef short bf16x8 __attribute__((ext_vector_type(8)));
typedef float f32x4 __attribute__((ext_vector_type(4)));

__device__ __forceinline__ float bf2f(unsigned int u) {
  union { unsigned int i; float f; } v; v.i = u << 16; return v.f;
}
__device__ __forceinline__ unsigned short f2bf(float f) {
  union { float f; unsigned int i; } v; v.f = f;
  unsigned int x = v.i;
  return (unsigned short)((x + 0x7fffu + ((x >> 16) & 1u)) >> 16);
}
// dtype-adaptive load: isbf=1 -> buffer is bf16 ushorts; else fp32 floats
__device__ __forceinline__ float ldf(const void* p, long i, int isbf) {
  if (isbf) return bf2f(((const unsigned short*)p)[i]);
  return ((const float*)p)[i];
}

// ---------------- K0: dtype probe ----------------
// bf16 N(0,1) data: even-index ushorts have exponent field in ~[0x66,0x82].
// fp32 data read as ushorts: even indices are uniform low-mantissa bits ->
// ~75% land outside [0x50,0x90). Count and vote.
__global__ __launch_bounds__(256) void k_detect(
    const unsigned short* __restrict__ x, int* __restrict__ flag) {
  __shared__ int bad;
  if (threadIdx.x == 0) bad = 0;
  __syncthreads();
  int cnt = 0;
  for (int i = threadIdx.x; i < 1024; i += 256) {
    unsigned short u = x[i * 2];
    int e = (u >> 7) & 0xFF;
    if (e >= 0x90 || (e > 0 && e <= 0x50)) ++cnt;
  }
  atomicAdd(&bad, cnt);
  __syncthreads();
  if (threadIdx.x == 0) flag[0] = (bad < 100) ? 1 : 0;
}

// ---------------- K0b: canonicalize MFMA weights to bf16 ----------------
struct WPtrs { const void* p[7]; };  // fpW1,fpW2,fpW3,gpW0,gpW1,gpW2,gpW3
__global__ __launch_bounds__(256) void k_cvt(
    WPtrs wp, const int* __restrict__ flag, unsigned short* __restrict__ Wb) {
  const int e0=4096, e1=12288, e2=28928, e3=62208, e4=127744, e5=258816, e6=587520;
  int t = blockIdx.x * 256 + threadIdx.x;
  if (t >= e6) return;
  int s, base;
  if      (t < e0) { s=0; base=0;  }
  else if (t < e1) { s=1; base=e0; }
  else if (t < e2) { s=2; base=e1; }
  else if (t < e3) { s=3; base=e2; }
  else if (t < e4) { s=4; base=e3; }
  else if (t < e5) { s=5; base=e4; }
  else             { s=6; base=e5; }
  int local = t - base;
  unsigned short u;
  if (flag[0]) u = ((const unsigned short*)wp.p[s])[local];
  else         u = f2bf(((const float*)wp.p[s])[local]);
  Wb[t] = u;
}

// ---------------- K1: top-3 assignment + cluster sums ----------------
__global__ __launch_bounds__(256) void k_assign(
    const void* __restrict__ x, const void* __restrict__ node,
    const int* __restrict__ flag, int* __restrict__ idx, float* __restrict__ csum) {
  __shared__ float nd[2][64];
  __shared__ float cs[192];   // [m][{sx,sy,cnt}]
  int isbf = flag[0];
  int tid = threadIdx.x;
  int b = blockIdx.x >> 4;
  int n = ((blockIdx.x & 15) << 8) + tid;
  if (tid < 128) nd[tid >> 6][tid & 63] = ldf(node, b * 128 + tid, isbf);
  if (tid < 192) cs[tid] = 0.f;
  __syncthreads();
  float x0 = ldf(x, b * 8192 + n, isbf);
  float x1 = ldf(x, b * 8192 + 4096 + n, isbf);
  float d0 = 1e30f, d1 = 1e30f, d2 = 1e30f;
  int m0 = 0, m1 = 0, m2 = 0;
#pragma unroll 8
  for (int m = 0; m < 64; ++m) {
    float dx = x0 - nd[0][m];
    float dy = x1 - nd[1][m];
    float d = __fmul_rn(dx, dx) + __fmul_rn(dy, dy);   // no contraction: match ref
    if (d < d0)      { d2=d1; m2=m1; d1=d0; m1=m0; d0=d; m0=m; }
    else if (d < d1) { d2=d1; m2=m1; d1=d;  m1=m; }
    else if (d < d2) { d2=d;  m2=m; }
  }
  long base = ((long)b * NN + n) * 3;
  idx[base] = m0; idx[base + 1] = m1; idx[base + 2] = m2;
  atomicAdd(&cs[m0*3+0], x0); atomicAdd(&cs[m0*3+1], x1); atomicAdd(&cs[m0*3+2], 1.f);
  atomicAdd(&cs[m1*3+0], x0); atomicAdd(&cs[m1*3+1], x1); atomicAdd(&cs[m1*3+2], 1.f);
  atomicAdd(&cs[m2*3+0], x0); atomicAdd(&cs[m2*3+1], x1); atomicAdd(&cs[m2*3+2], 1.f);
  __syncthreads();
  if (tid < 192) atomicAdd(&csum[b * 192 + tid], cs[tid]);
}

// ---------------- K2: means, rotated nodes, rowflags, prefix offsets ----------------
__global__ __launch_bounds__(256) void k_means(
    const float* __restrict__ csum, float* __restrict__ noderot,
    int* __restrict__ rowflag, int* __restrict__ off) {
  int t = threadIdx.x;            // 256 = (b,m)
  int b = t >> 6, m = t & 63;
  float s0 = csum[b*192 + m*3], s1 = csum[b*192 + m*3 + 1], c = csum[b*192 + m*3 + 2];
  float mx = s0 / (c + 1e-5f);
  float my = s1 / (c + 1e-5f);
  rowflag[b * 64 + m] = (c > 0.f) ? 1 : 0;
  for (int r = 0; r < 4; ++r) {
    float th = 1.5707964f * (float)r;
    float cr = cosf(th), sr = sinf(th);
    noderot[((b*4 + r)*2 + 0)*64 + m] = cr*mx - sr*my;
    noderot[((b*4 + r)*2 + 1)*64 + m] = sr*mx + cr*my;
  }
  if (m == 0) {                   // serial prefix per b (counts are exact floats)
    int acc = 0;
    for (int mm = 0; mm < 64; ++mm) {
      off[b*64 + mm] = acc;
      acc += (int)csum[b*192 + mm*3 + 2];
    }
  }
}

// ---------------- K3: counting-sort scatter: sorted[b][pos] = (m<<12)|n ----------------
__global__ __launch_bounds__(256) void k_scatter(
    const int* __restrict__ idx, const int* __restrict__ off,
    int* __restrict__ cursor, int* __restrict__ sorted) {
  int t = blockIdx.x * 256 + threadIdx.x;   // 16384 = BB*NN
  int b = t >> 12, n = t & 4095;
#pragma unroll
  for (int kk = 0; kk < 3; ++kk) {
    int m = idx[((long)b * NN + n) * 3 + kk];
    int pos = off[b*64 + m] + atomicAdd(&cursor[b*64 + m], 1);
    sorted[b * KNN + pos] = (m << 12) | n;
  }
}

// ---------------- K5: fused fp block (xdec -> 4 layers -> segment-max pool) ----------------
// grid (192, 16): 64 m-sorted columns per block, one br per blockIdx.y.
// Also writes feat0[br][128] for the (kk=0,n=0) column (empty-node substitute).
__global__ __launch_bounds__(256) void k_fused(
    const void* __restrict__ x, const int* __restrict__ sorted,
    const int* __restrict__ idx, const float* __restrict__ noderot,
    const int* __restrict__ flag,
    const void* __restrict__ fW0, const void* __restrict__ fb0,
    const unsigned short* __restrict__ Wb,
    const void* __restrict__ fb1, const void* __restrict__ fb2,
    const void* __restrict__ fb3,
    unsigned int* __restrict__ pooled, float* __restrict__ feat0) {
  __shared__ unsigned short Cs[64 * 136];   // [col][0..1]=xdec, [2..129]=h3
  __shared__ unsigned short Hs[64 * 72];    // h1 then h2 (stride 72 -> 144B, 16B-mult)
  __shared__ unsigned int pool[64 * 128];   // [m][row] segment max (uint bits, relu'd)
  __shared__ int mcol[64];                  // m | (is_col0 << 8)
  const unsigned short* fW1 = Wb;           // 64x64
  const unsigned short* fW2 = Wb + 4096;    // 128x64
  const unsigned short* fW3 = Wb + 12288;   // 128x130
  int isbf = flag[0];
  int tid = threadIdx.x, lane = tid & 63, wv = tid >> 6;
  int quad = lane >> 4, lr = lane & 15;
  int br = blockIdx.y, b = br >> 2, r = br & 3;
  for (int i = tid; i < 8192; i += 256) pool[i] = 0;
  if (tid < 64) {
    int e = sorted[b * KNN + blockIdx.x * 64 + tid];
    int m = e >> 12, n = e & 4095;
    int isz = (n == 0 && m == idx[(long)b * NN * 3]) ? 256 : 0;
    mcol[tid] = m | isz;
    float x0 = ldf(x, b*8192 + n, isbf), x1 = ldf(x, b*8192 + 4096 + n, isbf);
    float th = 1.5707964f * (float)r;
    float cr = cosf(th), sr = sinf(th);
    float xd0 = (cr*x0 - sr*x1) - noderot[(br*2 + 0)*64 + m];
    float xd1 = (sr*x0 + cr*x1) - noderot[(br*2 + 1)*64 + m];
    *(unsigned int*)&Cs[tid * 136] = (unsigned int)f2bf(xd0) | ((unsigned int)f2bf(xd1) << 16);
  }
  __syncthreads();
  // ----- layer0 (2 -> 64), VALU -----
  {
    int col = tid & 63, og = (tid >> 6) << 4;
    unsigned int xu = *(unsigned int*)&Cs[col * 136];
    float fx0 = bf2f(xu & 0xffff), fx1 = bf2f(xu >> 16);
    union { bf16x8 v; unsigned short s[8]; } o8[2];
#pragma unroll
    for (int j = 0; j < 16; ++j) {
      int o = og + j;
      float h = ldf(fb0, o, isbf) + ldf(fW0, o*2, isbf) * fx0 + ldf(fW0, o*2+1, isbf) * fx1;
      o8[j >> 3].s[j & 7] = f2bf(fmaxf(h, 0.f));
    }
    *(bf16x8*)&Hs[col*72 + og]     = o8[0].v;
    *(bf16x8*)&Hs[col*72 + og + 8] = o8[1].v;
  }
  __syncthreads();
  // ----- layer1 (64 -> 64), MFMA -----
  {
    int o0 = wv * 16;
    f32x4 acc[4];
    float bb4[4];
#pragma unroll
    for (int rr = 0; rr < 4; ++rr) bb4[rr] = ldf(fb1, o0 + quad*4 + rr, isbf);
#pragma unroll
    for (int nt = 0; nt < 4; ++nt) acc[nt] = (f32x4){bb4[0], bb4[1], bb4[2], bb4[3]};
#pragma unroll
    for (int ks = 0; ks < 64; ks += 32) {
      bf16x8 a = *(const bf16x8*)(fW1 + (o0 + lr)*64 + ks + quad*8);
#pragma unroll
      for (int nt = 0; nt < 4; ++nt) {
        bf16x8 bf = *(bf16x8*)&Hs[(nt*16 + lr)*72 + ks + quad*8];
        acc[nt] = __builtin_amdgcn_mfma_f32_16x16x32_bf16(a, bf, acc[nt], 0, 0, 0);
      }
    }
    __syncthreads();  // everyone done READING Hs
#pragma unroll
    for (int nt = 0; nt < 4; ++nt) {
      int col = nt*16 + lr;
      union { unsigned long long u; unsigned short s[4]; } pk;
#pragma unroll
      for (int rr = 0; rr < 4; ++rr) pk.s[rr] = f2bf(fmaxf(acc[nt][rr], 0.f));
      *(unsigned long long*)&Hs[col*72 + o0 + quad*4] = pk.u;
    }
  }
  __syncthreads();
  // ----- layer2 (64 -> 128), MFMA, output into Cs[2..129] -----
#pragma unroll
  for (int p2 = 0; p2 < 2; ++p2) {
    int o0 = p2*64 + wv*16;
    f32x4 acc[4];
    float bb4[4];
#pragma unroll
    for (int rr = 0; rr < 4; ++rr) bb4[rr] = ldf(fb2, o0 + quad*4 + rr, isbf);
#pragma unroll
    for (int nt = 0; nt < 4; ++nt) acc[nt] = (f32x4){bb4[0], bb4[1], bb4[2], bb4[3]};
#pragma unroll
    for (int ks = 0; ks < 64; ks += 32) {
      bf16x8 a = *(const bf16x8*)(fW2 + (o0 + lr)*64 + ks + quad*8);
#pragma unroll
      for (int nt = 0; nt < 4; ++nt) {
        bf16x8 bf = *(bf16x8*)&Hs[(nt*16 + lr)*72 + ks + quad*8];
        acc[nt] = __builtin_amdgcn_mfma_f32_16x16x32_bf16(a, bf, acc[nt], 0, 0, 0);
      }
    }
#pragma unroll
    for (int nt = 0; nt < 4; ++nt) {
      int col = nt*16 + lr;
      int o = o0 + quad*4;
      unsigned int w0 = (unsigned int)f2bf(fmaxf(acc[nt][0], 0.f)) |
                        ((unsigned int)f2bf(fmaxf(acc[nt][1], 0.f)) << 16);
      unsigned int w1 = (unsigned int)f2bf(fmaxf(acc[nt][2], 0.f)) |
                        ((unsigned int)f2bf(fmaxf(acc[nt][3], 0.f)) << 16);
      *(unsigned int*)&Cs[col*136 + 2 + o] = w0;   // 2+o even -> 4B aligned
      *(unsigned int*)&Cs[col*136 + 4 + o] = w1;
    }
  }
  __syncthreads();
  // ----- layer3 (130 -> 128), MFMA + 2-ch tail, then LDS segment-max pool -----
#pragma unroll
  for (int p3 = 0; p3 < 2; ++p3) {
    int o0 = p3*64 + wv*16;
    f32x4 acc[4];
    float bb4[4];
#pragma unroll
    for (int rr = 0; rr < 4; ++rr) bb4[rr] = ldf(fb3, o0 + quad*4 + rr, isbf);
#pragma unroll
    for (int nt = 0; nt < 4; ++nt) acc[nt] = (f32x4){bb4[0], bb4[1], bb4[2], bb4[3]};
#pragma unroll
    for (int ks = 0; ks < 128; ks += 32) {
      union { bf16x8 v; unsigned int u[4]; } au;
      const unsigned int* ap = (const unsigned int*)(fW3 + (long)(o0 + lr)*130 + ks + quad*8);
      au.u[0] = ap[0]; au.u[1] = ap[1]; au.u[2] = ap[2]; au.u[3] = ap[3];
#pragma unroll
      for (int nt = 0; nt < 4; ++nt) {
        bf16x8 bf = *(bf16x8*)&Cs[(nt*16 + lr)*136 + ks + quad*8];
        acc[nt] = __builtin_amdgcn_mfma_f32_16x16x32_bf16(au.v, bf, acc[nt], 0, 0, 0);
      }
    }
#pragma unroll
    for (int rr = 0; rr < 4; ++rr) {   // K tail: channels 128..129
      int o = o0 + quad*4 + rr;
      unsigned int wu = *(const unsigned int*)(fW3 + (long)o*130 + 128);
      float w0 = bf2f(wu & 0xffff), w1 = bf2f(wu >> 16);
#pragma unroll
      for (int nt = 0; nt < 4; ++nt) {
        unsigned int bu = *(unsigned int*)&Cs[(nt*16 + lr)*136 + 128];
        acc[nt][rr] += w0 * bf2f(bu & 0xffff) + w1 * bf2f(bu >> 16);
      }
    }
#pragma unroll
    for (int nt = 0; nt < 4; ++nt) {
      int mc = mcol[nt*16 + lr];
      int m = mc & 255;
#pragma unroll
      for (int rr = 0; rr < 4; ++rr) {
        float v = fmaxf(acc[nt][rr], 0.f);
        atomicMax(&pool[m*128 + o0 + quad*4 + rr], __float_as_uint(v));
        if (mc & 256) feat0[br*128 + o0 + quad*4 + rr] = v;
      }
    }
  }
  __syncthreads();
  // ----- merge block-local pool to global (atomicMax with 0 is a no-op) -----
  for (int i = tid; i < 8192; i += 256) {
    unsigned int u = pool[i];
    if (u) atomicMax(&pooled[(((long)br*64 + (i >> 7)) << 7) + (i & 127)], u);
  }
}

// ---------------- K6: build gp input AG [col=br*64+m][648] ----------------
__global__ __launch_bounds__(256) void k_finalize(
    const unsigned int* __restrict__ pooled, const float* __restrict__ feat0,
    const int* __restrict__ rowflag, const float* __restrict__ noderot,
    unsigned short* __restrict__ AG) {
  int t = blockIdx.x * 256 + threadIdx.x;  // 131072
  int col = t >> 7, o = t & 127;
  int br = col >> 6, m = col & 63, b = br >> 2;
  float v = __uint_as_float(pooled[((long)col << 7) + o]);
  if (!rowflag[b*64 + m]) v = feat0[br*128 + o];
  AG[(long)col*648 + 2 + o] = f2bf(v);
  if (o < 2) AG[(long)col*648 + o] = f2bf(noderot[(br*2 + o)*64 + m]);
}

// ---------------- generic MFMA GEMM (gp layers) ----------------
// Out[o][p] = relu(bias[o] + sum_k W[o][k]*B[p][k]); W is canonical bf16.
// EPI 0: store bf16 Out[p*OSTR + OOFF + o]; EPI 2: relu+max over 64 cols -> atomicMax
template<int KW, int KMAIN, bool REM2, int BSTR, int OSTR, int OOFF, int EPI>
__global__ __launch_bounds__(256) void k_gemm(
    const unsigned short* __restrict__ W, const void* __restrict__ bias,
    const int* __restrict__ flag,
    const unsigned short* __restrict__ Bb, unsigned short* __restrict__ Out,
    unsigned int* __restrict__ outmax) {
  int isbf = flag[0];
  int lane = threadIdx.x & 63;
  int wv = threadIdx.x >> 6;
  int quad = lane >> 4, lr = lane & 15;
  int o0 = blockIdx.y * 64 + wv * 16;
  long p0 = (long)blockIdx.x * 64;
  float bia[4];
#pragma unroll
  for (int rr = 0; rr < 4; ++rr) bia[rr] = ldf(bias, o0 + quad*4 + rr, isbf);
  f32x4 acc[4];
#pragma unroll
  for (int nt = 0; nt < 4; ++nt) acc[nt] = (f32x4){bia[0], bia[1], bia[2], bia[3]};
  const unsigned short* arow = W + (long)(o0 + lr) * KW;
  for (int ks = 0; ks < KMAIN; ks += 32) {
    bf16x8 a;
    if constexpr ((KW % 8) == 0) {
      a = *(const bf16x8*)(arow + ks + quad*8);
    } else {
      union { bf16x8 v; unsigned int u[4]; } au;
      const unsigned int* ap = (const unsigned int*)(arow + ks + quad*8);  // 4B aligned
      au.u[0] = ap[0]; au.u[1] = ap[1]; au.u[2] = ap[2]; au.u[3] = ap[3];
      a = au.v;
    }
#pragma unroll
    for (int nt = 0; nt < 4; ++nt) {
      bf16x8 bf = *(const bf16x8*)(Bb + (p0 + nt*16 + lr) * BSTR + ks + quad*8);
      acc[nt] = __builtin_amdgcn_mfma_f32_16x16x32_bf16(a, bf, acc[nt], 0, 0, 0);
    }
  }
  if constexpr (REM2) {
#pragma unroll
    for (int rr = 0; rr < 4; ++rr) {
      int o = o0 + quad*4 + rr;
      unsigned int wu = *(const unsigned int*)(W + (long)o * KW + KMAIN);
      float w0 = bf2f(wu & 0xffff), w1 = bf2f(wu >> 16);
#pragma unroll
      for (int nt = 0; nt < 4; ++nt) {
        long p = p0 + nt*16 + lr;
        unsigned int bu = *(const unsigned int*)(Bb + p * BSTR + KMAIN);
        acc[nt][rr] += w0 * bf2f(bu & 0xffff) + w1 * bf2f(bu >> 16);
      }
    }
  }
  if constexpr (EPI == 0) {
#pragma unroll
    for (int nt = 0; nt < 4; ++nt) {
      long p = p0 + nt*16 + lr;
      unsigned short v0 = f2bf(fmaxf(acc[nt][0], 0.f));
      unsigned short v1 = f2bf(fmaxf(acc[nt][1], 0.f));
      unsigned short v2 = f2bf(fmaxf(acc[nt][2], 0.f));
      unsigned short v3 = f2bf(fmaxf(acc[nt][3], 0.f));
      unsigned short* op = Out + p * OSTR + OOFF + o0 + quad*4;
      if constexpr (((OOFF * 2) % 8) == 0) {
        union { unsigned long long u; unsigned short s[4]; } pk;
        pk.s[0] = v0; pk.s[1] = v1; pk.s[2] = v2; pk.s[3] = v3;
        *(unsigned long long*)op = pk.u;
      } else {
        *(unsigned int*)op       = (unsigned int)v0 | ((unsigned int)v1 << 16);
        *(unsigned int*)(op + 2) = (unsigned int)v2 | ((unsigned int)v3 << 16);
      }
    }
  } else {  // EPI == 2
#pragma unroll
    for (int rr = 0; rr < 4; ++rr) {
      float v = fmaxf(fmaxf(acc[0][rr], acc[1][rr]), fmaxf(acc[2][rr], acc[3][rr]));
      v = fmaxf(v, 0.f);
      v = fmaxf(v, __shfl_xor(v, 1, 64));
      v = fmaxf(v, __shfl_xor(v, 2, 64));
      v = fmaxf(v, __shfl_xor(v, 4, 64));
      v = fmaxf(v, __shfl_xor(v, 8, 64));
      if (lr == 0) {
        int bb2 = (int)(blockIdx.x >> 2);   // blockIdx.x = br
        atomicMax(&outmax[bb2 * FF + o0 + quad*4 + rr], __float_as_uint(v));
      }
    }
  }
}

// ---------------- K7: output convert (dtype-adaptive) ----------------
__global__ __launch_bounds__(256) void k_out(
    const unsigned int* __restrict__ outmax, const int* __restrict__ flag,
    void* __restrict__ out) {
  int t = blockIdx.x * 256 + threadIdx.x;
  float v = __uint_as_float(outmax[t]);
  if (flag[0]) ((unsigned short*)out)[t] = f2bf(v);
  else         ((float*)out)[t] = v;
}

// ---------------- host ----------------
extern "C" void kernel_launch(void* const* d_in, const int* in_sizes, int n_in,
                              void* d_out, int out_size, void* d_ws, size_t ws_size,
                              hipStream_t stream) {
  const void* x    = d_in[0];
  const void* node = d_in[2];
  const void* fpW0 = d_in[4];  const void* fpb0 = d_in[5];
  const void* fpW1 = d_in[6];  const void* fpb1 = d_in[7];
  const void* fpW2 = d_in[8];  const void* fpb2 = d_in[9];
  const void* fpW3 = d_in[10]; const void* fpb3 = d_in[11];
  const void* gpW0 = d_in[12]; const void* gpb0 = d_in[13];
  const void* gpW1 = d_in[14]; const void* gpb1 = d_in[15];
  const void* gpW2 = d_in[16]; const void* gpb2 = d_in[17];
  const void* gpW3 = d_in[18]; const void* gpb3 = d_in[19];

  // workspace layout (~4.5 MB total; zeroed region first)
  char* ws = (char*)d_ws;
  int*            flag    = (int*)(ws + 0);            //    256 (4 used)
  float*          csum    = (float*)(ws + 256);        //   3072
  unsigned int*   outmax  = (unsigned int*)(ws + 3328);//   8192
  int*            cursor  = (int*)(ws + 11520);        //   1024
  unsigned int*   pooled  = (unsigned int*)(ws + 12544);// 524288
  // ---- end of memset region (536832 B) ----
  int*            idx     = (int*)(ws + 536832);       // 196608
  int*            off     = (int*)(ws + 733440);       //   1024
  float*          noderot = (float*)(ws + 734464);     //   8192
  int*            rowflag = (int*)(ws + 742656);       //   1024
  int*            sorted  = (int*)(ws + 743680);       // 196608
  float*          feat0   = (float*)(ws + 940288);     //   8192
  unsigned short* AG      = (unsigned short*)(ws + 948480);   // 1327104
  unsigned short* Hg1     = (unsigned short*)(ws + 2275584);  // 524288
  unsigned short* Hg2     = (unsigned short*)(ws + 2799872);  // 524288
  unsigned short* Wb      = (unsigned short*)(ws + 3324160);  // 1175040

  hipMemsetAsync(ws, 0, 536832, stream);

  k_detect<<<1, 256, 0, stream>>>((const unsigned short*)x, flag);
  WPtrs wp; wp.p[0]=fpW1; wp.p[1]=fpW2; wp.p[2]=fpW3; wp.p[3]=gpW0;
  wp.p[4]=gpW1; wp.p[5]=gpW2; wp.p[6]=gpW3;
  k_cvt<<<2295, 256, 0, stream>>>(wp, flag, Wb);

  k_assign<<<64, 256, 0, stream>>>(x, node, flag, idx, csum);
  k_means<<<1, 256, 0, stream>>>(csum, noderot, rowflag, off);
  k_scatter<<<64, 256, 0, stream>>>(idx, off, cursor, sorted);
  k_fused<<<dim3(192, 16), 256, 0, stream>>>(x, sorted, idx, noderot, flag,
                                             fpW0, fpb0, Wb, fpb1, fpb2, fpb3,
                                             pooled, feat0);
  k_finalize<<<512, 256, 0, stream>>>(pooled, feat0, rowflag, noderot, AG);

  // gp layers over 1024 columns (br*64+m); weights from canonical bf16 Wb
  const unsigned short* gW0 = Wb + 28928;
  const unsigned short* gW1 = Wb + 62208;
  const unsigned short* gW2 = Wb + 127744;
  const unsigned short* gW3 = Wb + 258816;
  k_gemm<130, 128, true, 648, 256, 0, 0><<<dim3(16, 4), 256, 0, stream>>>(gW0, gpb0, flag, AG, Hg1, nullptr);
  k_gemm<256, 256, false, 256, 256, 0, 0><<<dim3(16, 4), 256, 0, stream>>>(gW1, gpb1, flag, Hg1, Hg2, nullptr);
  k_gemm<256, 256, false, 256, 648, 130, 0><<<dim3(16, 8), 256, 0, stream>>>(gW2, gpb2, flag, Hg2, AG, nullptr);
  k_gemm<642, 640, true, 648, 0, 0, 2><<<dim3(16, 8), 256, 0, stream>>>(gW3, gpb3, flag, AG, nullptr, outmax);

  k_out<<<8, 256, 0, stream>>>(outmax, flag, d_out);
}

// Round 4
// 201.021 us; speedup vs baseline: 1.3655x; 1.3655x over previous
//
#include <hip/hip_runtime.h>
#include <stdint.h>

// ---------------- problem constants ----------------
#define BB 4
#define RR 4
#define NN 4096
#define MM 64
#define KK 3
#define KNN 12288           // KK*NN
#define BRR 16              // BB*RR
#define FF 512

typedef short bf16x8 __attribute__((ext_vector_type(8)));
typedef float f32x4 __attribute__((ext_vector_type(4)));

__device__ __forceinline__ float bf2f(unsigned int u) {
  union { unsigned int i; float f; } v; v.i = u << 16; return v.f;
}
__device__ __forceinline__ unsigned short f2bf(float f) {
  union { float f; unsigned int i; } v; v.f = f;
  unsigned int x = v.i;
  return (unsigned short)((x + 0x7fffu + ((x >> 16) & 1u)) >> 16);
}
// dtype-adaptive load: isbf=1 -> buffer is bf16 ushorts; else fp32 floats
__device__ __forceinline__ float ldf(const void* p, long i, int isbf) {
  if (isbf) return bf2f(((const unsigned short*)p)[i]);
  return ((const float*)p)[i];
}

// ---------------- K0: dtype probe ----------------
__global__ __launch_bounds__(256) void k_detect(
    const unsigned short* __restrict__ x, int* __restrict__ flag) {
  __shared__ int bad;
  if (threadIdx.x == 0) bad = 0;
  __syncthreads();
  int cnt = 0;
  for (int i = threadIdx.x; i < 1024; i += 256) {
    unsigned short u = x[i * 2];
    int e = (u >> 7) & 0xFF;
    if (e >= 0x90 || (e > 0 && e <= 0x50)) ++cnt;
  }
  atomicAdd(&bad, cnt);
  __syncthreads();
  if (threadIdx.x == 0) flag[0] = (bad < 100) ? 1 : 0;
}

// ---------------- K0b: canonicalize MFMA weights to bf16 ----------------
struct WPtrs { const void* p[7]; };  // fpW1,fpW2,fpW3,gpW0,gpW1,gpW2,gpW3
__global__ __launch_bounds__(256) void k_cvt(
    WPtrs wp, const int* __restrict__ flag, unsigned short* __restrict__ Wb) {
  const int e0=4096, e1=12288, e2=28928, e3=62208, e4=127744, e5=258816, e6=587520;
  int t = blockIdx.x * 256 + threadIdx.x;
  if (t >= e6) return;
  int s, base;
  if      (t < e0) { s=0; base=0;  }
  else if (t < e1) { s=1; base=e0; }
  else if (t < e2) { s=2; base=e1; }
  else if (t < e3) { s=3; base=e2; }
  else if (t < e4) { s=4; base=e3; }
  else if (t < e5) { s=5; base=e4; }
  else             { s=6; base=e5; }
  int local = t - base;
  unsigned short u;
  if (flag[0]) u = ((const unsigned short*)wp.p[s])[local];
  else         u = f2bf(((const float*)wp.p[s])[local]);
  Wb[t] = u;
}

// ---------------- K1: top-3 assignment + cluster sums + per-block histogram ----------------
__global__ __launch_bounds__(256) void k_assign(
    const void* __restrict__ x, const void* __restrict__ node,
    const int* __restrict__ flag, int* __restrict__ idx, float* __restrict__ csum,
    int* __restrict__ blkcnt) {
  __shared__ float nd[2][64];
  __shared__ float cs[192];   // [m][{sx,sy,cnt}]
  int isbf = flag[0];
  int tid = threadIdx.x;
  int b = blockIdx.x >> 4;
  int n = ((blockIdx.x & 15) << 8) + tid;
  if (tid < 128) nd[tid >> 6][tid & 63] = ldf(node, b * 128 + tid, isbf);
  if (tid < 192) cs[tid] = 0.f;
  __syncthreads();
  float x0 = ldf(x, b * 8192 + n, isbf);
  float x1 = ldf(x, b * 8192 + 4096 + n, isbf);
  float d0 = 1e30f, d1 = 1e30f, d2 = 1e30f;
  int m0 = 0, m1 = 0, m2 = 0;
#pragma unroll 8
  for (int m = 0; m < 64; ++m) {
    float dx = x0 - nd[0][m];
    float dy = x1 - nd[1][m];
    float d = __fmul_rn(dx, dx) + __fmul_rn(dy, dy);   // no contraction: match ref
    if (d < d0)      { d2=d1; m2=m1; d1=d0; m1=m0; d0=d; m0=m; }
    else if (d < d1) { d2=d1; m2=m1; d1=d;  m1=m; }
    else if (d < d2) { d2=d;  m2=m; }
  }
  long base = ((long)b * NN + n) * 3;
  idx[base] = m0; idx[base + 1] = m1; idx[base + 2] = m2;
  atomicAdd(&cs[m0*3+0], x0); atomicAdd(&cs[m0*3+1], x1); atomicAdd(&cs[m0*3+2], 1.f);
  atomicAdd(&cs[m1*3+0], x0); atomicAdd(&cs[m1*3+1], x1); atomicAdd(&cs[m1*3+2], 1.f);
  atomicAdd(&cs[m2*3+0], x0); atomicAdd(&cs[m2*3+1], x1); atomicAdd(&cs[m2*3+2], 1.f);
  __syncthreads();
  if (tid < 192) atomicAdd(&csum[b * 192 + tid], cs[tid]);
  if (tid < 64) blkcnt[blockIdx.x * 64 + tid] = (int)cs[tid*3 + 2];
}

// ---------------- K2: means, rotated nodes, rowflags, prefix offsets ----------------
__global__ __launch_bounds__(256) void k_means(
    const float* __restrict__ csum, const int* __restrict__ blkcnt,
    float* __restrict__ noderot, int* __restrict__ rowflag,
    int* __restrict__ off, int* __restrict__ blkoff) {
  int t = threadIdx.x;            // 256 = (b,m)
  int b = t >> 6, m = t & 63;
  float s0 = csum[b*192 + m*3], s1 = csum[b*192 + m*3 + 1], c = csum[b*192 + m*3 + 2];
  float mx = s0 / (c + 1e-5f);
  float my = s1 / (c + 1e-5f);
  rowflag[b * 64 + m] = (c > 0.f) ? 1 : 0;
  for (int r = 0; r < 4; ++r) {
    float th = 1.5707964f * (float)r;
    float cr = cosf(th), sr = sinf(th);
    noderot[((b*4 + r)*2 + 0)*64 + m] = cr*mx - sr*my;
    noderot[((b*4 + r)*2 + 1)*64 + m] = sr*mx + cr*my;
  }
  if (m == 0) {                   // serial prefix per b (counts are exact floats)
    int acc = 0;
    for (int mm = 0; mm < 64; ++mm) {
      off[b*64 + mm] = acc;
      acc += (int)csum[b*192 + mm*3 + 2];
    }
  }
  __syncthreads();
  int base = off[b*64 + m];       // per-(block,m) bases for atomic-free scatter
  for (int blk = 0; blk < 16; ++blk) {
    blkoff[(b*16 + blk)*64 + m] = base;
    base += blkcnt[(b*16 + blk)*64 + m];
  }
}

// ---------------- K3: counting-sort scatter (LDS cursors only) ----------------
__global__ __launch_bounds__(256) void k_scatter(
    const int* __restrict__ idx, const int* __restrict__ blkoff,
    int* __restrict__ sorted) {
  __shared__ int lc[64];
  int tid = threadIdx.x;
  int blk = blockIdx.x;           // b*16 + chunk (matches k_assign)
  int b = blk >> 4;
  int n = ((blk & 15) << 8) + tid;
  if (tid < 64) lc[tid] = 0;
  __syncthreads();
#pragma unroll
  for (int kk = 0; kk < 3; ++kk) {
    int m = idx[((long)b * NN + n) * 3 + kk];
    int pos = atomicAdd(&lc[m], 1);                 // LDS atomic, order irrelevant
    sorted[b * KNN + blkoff[blk*64 + m] + pos] = (m << 12) | n;
  }
}

// ---------------- K5: fused fp block (xdec -> 4 layers -> run-scan segment max) --------
// grid (192, 16): 64 m-sorted columns per block, one br per blockIdx.y.
__global__ __launch_bounds__(256) void k_fused(
    const void* __restrict__ x, const int* __restrict__ sorted,
    const int* __restrict__ idx, const float* __restrict__ noderot,
    const int* __restrict__ flag,
    const void* __restrict__ fW0, const void* __restrict__ fb0,
    const unsigned short* __restrict__ Wb,
    const void* __restrict__ fb1, const void* __restrict__ fb2,
    const void* __restrict__ fb3,
    unsigned int* __restrict__ pooled, float* __restrict__ feat0) {
  __shared__ unsigned short Cs[64 * 136];   // [col][0..1]=xdec, [2..129]=h2; later [0..127]=feat
  __shared__ unsigned short Hs[64 * 72];    // h1 (stride 72 -> 144B, 16B-mult)
  __shared__ int mcol[64];                  // m | (is_col0 << 8)
  const unsigned short* fW1 = Wb;           // 64x64
  const unsigned short* fW2 = Wb + 4096;    // 128x64
  const unsigned short* fW3 = Wb + 12288;   // 128x130
  int isbf = flag[0];
  int tid = threadIdx.x, lane = tid & 63, wv = tid >> 6;
  int quad = lane >> 4, lr = lane & 15;
  int br = blockIdx.y, b = br >> 2, r = br & 3;
  if (tid < 64) {
    int e = sorted[b * KNN + blockIdx.x * 64 + tid];
    int m = e >> 12, n = e & 4095;
    int isz = (n == 0 && m == idx[(long)b * NN * 3]) ? 256 : 0;
    mcol[tid] = m | isz;
    float x0 = ldf(x, b*8192 + n, isbf), x1 = ldf(x, b*8192 + 4096 + n, isbf);
    float th = 1.5707964f * (float)r;
    float cr = cosf(th), sr = sinf(th);
    float xd0 = (cr*x0 - sr*x1) - noderot[(br*2 + 0)*64 + m];
    float xd1 = (sr*x0 + cr*x1) - noderot[(br*2 + 1)*64 + m];
    *(unsigned int*)&Cs[tid * 136] = (unsigned int)f2bf(xd0) | ((unsigned int)f2bf(xd1) << 16);
  }
  __syncthreads();
  // ----- layer0 (2 -> 64), VALU -----
  {
    int col = tid & 63, og = (tid >> 6) << 4;
    unsigned int xu = *(unsigned int*)&Cs[col * 136];
    float fx0 = bf2f(xu & 0xffff), fx1 = bf2f(xu >> 16);
    union { bf16x8 v; unsigned short s[8]; } o8[2];
#pragma unroll
    for (int j = 0; j < 16; ++j) {
      int o = og + j;
      float h = ldf(fb0, o, isbf) + ldf(fW0, o*2, isbf) * fx0 + ldf(fW0, o*2+1, isbf) * fx1;
      o8[j >> 3].s[j & 7] = f2bf(fmaxf(h, 0.f));
    }
    *(bf16x8*)&Hs[col*72 + og]     = o8[0].v;
    *(bf16x8*)&Hs[col*72 + og + 8] = o8[1].v;
  }
  __syncthreads();
  // ----- layer1 (64 -> 64), MFMA -----
  {
    int o0 = wv * 16;
    f32x4 acc[4];
    float bb4[4];
#pragma unroll
    for (int rr = 0; rr < 4; ++rr) bb4[rr] = ldf(fb1, o0 + quad*4 + rr, isbf);
#pragma unroll
    for (int nt = 0; nt < 4; ++nt) acc[nt] = (f32x4){bb4[0], bb4[1], bb4[2], bb4[3]};
#pragma unroll
    for (int ks = 0; ks < 64; ks += 32) {
      bf16x8 a = *(const bf16x8*)(fW1 + (o0 + lr)*64 + ks + quad*8);
#pragma unroll
      for (int nt = 0; nt < 4; ++nt) {
        bf16x8 bf = *(bf16x8*)&Hs[(nt*16 + lr)*72 + ks + quad*8];
        acc[nt] = __builtin_amdgcn_mfma_f32_16x16x32_bf16(a, bf, acc[nt], 0, 0, 0);
      }
    }
    __syncthreads();  // everyone done READING Hs
#pragma unroll
    for (int nt = 0; nt < 4; ++nt) {
      int col = nt*16 + lr;
      union { unsigned long long u; unsigned short s[4]; } pk;
#pragma unroll
      for (int rr = 0; rr < 4; ++rr) pk.s[rr] = f2bf(fmaxf(acc[nt][rr], 0.f));
      *(unsigned long long*)&Hs[col*72 + o0 + quad*4] = pk.u;
    }
  }
  __syncthreads();
  // ----- layer2 (64 -> 128), MFMA, output into Cs[2..129] -----
#pragma unroll
  for (int p2 = 0; p2 < 2; ++p2) {
    int o0 = p2*64 + wv*16;
    f32x4 acc[4];
    float bb4[4];
#pragma unroll
    for (int rr = 0; rr < 4; ++rr) bb4[rr] = ldf(fb2, o0 + quad*4 + rr, isbf);
#pragma unroll
    for (int nt = 0; nt < 4; ++nt) acc[nt] = (f32x4){bb4[0], bb4[1], bb4[2], bb4[3]};
#pragma unroll
    for (int ks = 0; ks < 64; ks += 32) {
      bf16x8 a = *(const bf16x8*)(fW2 + (o0 + lr)*64 + ks + quad*8);
#pragma unroll
      for (int nt = 0; nt < 4; ++nt) {
        bf16x8 bf = *(bf16x8*)&Hs[(nt*16 + lr)*72 + ks + quad*8];
        acc[nt] = __builtin_amdgcn_mfma_f32_16x16x32_bf16(a, bf, acc[nt], 0, 0, 0);
      }
    }
#pragma unroll
    for (int nt = 0; nt < 4; ++nt) {
      int col = nt*16 + lr;
      int o = o0 + quad*4;
      unsigned int w0 = (unsigned int)f2bf(fmaxf(acc[nt][0], 0.f)) |
                        ((unsigned int)f2bf(fmaxf(acc[nt][1], 0.f)) << 16);
      unsigned int w1 = (unsigned int)f2bf(fmaxf(acc[nt][2], 0.f)) |
                        ((unsigned int)f2bf(fmaxf(acc[nt][3], 0.f)) << 16);
      *(unsigned int*)&Cs[col*136 + 2 + o] = w0;   // 2+o even -> 4B aligned
      *(unsigned int*)&Cs[col*136 + 4 + o] = w1;
    }
  }
  __syncthreads();
  // ----- layer3 (130 -> 128): both halves in registers, then feats -> Cs[0..127] -----
  f32x4 acc3[2][4];
#pragma unroll
  for (int p3 = 0; p3 < 2; ++p3) {
    int o0 = p3*64 + wv*16;
    float bb4[4];
#pragma unroll
    for (int rr = 0; rr < 4; ++rr) bb4[rr] = ldf(fb3, o0 + quad*4 + rr, isbf);
#pragma unroll
    for (int nt = 0; nt < 4; ++nt) acc3[p3][nt] = (f32x4){bb4[0], bb4[1], bb4[2], bb4[3]};
#pragma unroll
    for (int ks = 0; ks < 128; ks += 32) {
      union { bf16x8 v; unsigned int u[4]; } au;
      const unsigned int* ap = (const unsigned int*)(fW3 + (long)(o0 + lr)*130 + ks + quad*8);
      au.u[0] = ap[0]; au.u[1] = ap[1]; au.u[2] = ap[2]; au.u[3] = ap[3];
#pragma unroll
      for (int nt = 0; nt < 4; ++nt) {
        bf16x8 bf = *(bf16x8*)&Cs[(nt*16 + lr)*136 + ks + quad*8];
        acc3[p3][nt] = __builtin_amdgcn_mfma_f32_16x16x32_bf16(au.v, bf, acc3[p3][nt], 0, 0, 0);
      }
    }
#pragma unroll
    for (int rr = 0; rr < 4; ++rr) {   // K tail: channels 128..129 (NOT overwritten below)
      int o = o0 + quad*4 + rr;
      unsigned int wu = *(const unsigned int*)(fW3 + (long)o*130 + 128);
      float w0 = bf2f(wu & 0xffff), w1 = bf2f(wu >> 16);
#pragma unroll
      for (int nt = 0; nt < 4; ++nt) {
        unsigned int bu = *(unsigned int*)&Cs[(nt*16 + lr)*136 + 128];
        acc3[p3][nt][rr] += w0 * bf2f(bu & 0xffff) + w1 * bf2f(bu >> 16);
      }
    }
  }
  __syncthreads();   // ALL Cs reads complete before feat overwrite
#pragma unroll
  for (int p3 = 0; p3 < 2; ++p3) {
    int o0 = p3*64 + wv*16;
#pragma unroll
    for (int nt = 0; nt < 4; ++nt) {
      int col = nt*16 + lr;
      union { unsigned long long u; unsigned short s[4]; } pk;
#pragma unroll
      for (int rr = 0; rr < 4; ++rr) pk.s[rr] = f2bf(fmaxf(acc3[p3][nt][rr], 0.f));
      *(unsigned long long*)&Cs[col*136 + o0 + quad*4] = pk.u;   // 8B aligned
    }
  }
  __syncthreads();
  // ----- run-scan segment max: thread = (row o, col-half h); runs contiguous (sorted) ---
  {
    int o = tid & 127, h = tid >> 7;
    int c0 = h * 32;
    int curm = mcol[c0] & 255;
    float v = 0.f;                       // relu'd values >= 0
    for (int c = c0; c < c0 + 32; ++c) {
      int mc = mcol[c];
      int mm = mc & 255;
      float f = bf2f(Cs[c*136 + o]);
      if (mm != curm) {
        atomicMax(&pooled[(((long)br*64 + curm) << 7) + o], __float_as_uint(v));
        curm = mm; v = 0.f;
      }
      v = fmaxf(v, f);
      if (mc & 256) feat0[br*128 + o] = f;   // (kk=0,n=0) column -> empty-node substitute
    }
    atomicMax(&pooled[(((long)br*64 + curm) << 7) + o], __float_as_uint(v));
  }
}

// ---------------- K6: build gp input AG [col=br*64+m][648] ----------------
__global__ __launch_bounds__(256) void k_finalize(
    const unsigned int* __restrict__ pooled, const float* __restrict__ feat0,
    const int* __restrict__ rowflag, const float* __restrict__ noderot,
    unsigned short* __restrict__ AG) {
  int t = blockIdx.x * 256 + threadIdx.x;  // 131072
  int col = t >> 7, o = t & 127;
  int br = col >> 6, m = col & 63, b = br >> 2;
  float v = __uint_as_float(pooled[((long)col << 7) + o]);
  if (!rowflag[b*64 + m]) v = feat0[br*128 + o];
  AG[(long)col*648 + 2 + o] = f2bf(v);
  if (o < 2) AG[(long)col*648 + o] = f2bf(noderot[(br*2 + o)*64 + m]);
}

// ---------------- generic MFMA GEMM (gp layers) ----------------
template<int KW, int KMAIN, bool REM2, int BSTR, int OSTR, int OOFF, int EPI>
__global__ __launch_bounds__(256) void k_gemm(
    const unsigned short* __restrict__ W, const void* __restrict__ bias,
    const int* __restrict__ flag,
    const unsigned short* __restrict__ Bb, unsigned short* __restrict__ Out,
    unsigned int* __restrict__ outmax) {
  int isbf = flag[0];
  int lane = threadIdx.x & 63;
  int wv = threadIdx.x >> 6;
  int quad = lane >> 4, lr = lane & 15;
  int o0 = blockIdx.y * 64 + wv * 16;
  long p0 = (long)blockIdx.x * 64;
  float bia[4];
#pragma unroll
  for (int rr = 0; rr < 4; ++rr) bia[rr] = ldf(bias, o0 + quad*4 + rr, isbf);
  f32x4 acc[4];
#pragma unroll
  for (int nt = 0; nt < 4; ++nt) acc[nt] = (f32x4){bia[0], bia[1], bia[2], bia[3]};
  const unsigned short* arow = W + (long)(o0 + lr) * KW;
  for (int ks = 0; ks < KMAIN; ks += 32) {
    bf16x8 a;
    if constexpr ((KW % 8) == 0) {
      a = *(const bf16x8*)(arow + ks + quad*8);
    } else {
      union { bf16x8 v; unsigned int u[4]; } au;
      const unsigned int* ap = (const unsigned int*)(arow + ks + quad*8);  // 4B aligned
      au.u[0] = ap[0]; au.u[1] = ap[1]; au.u[2] = ap[2]; au.u[3] = ap[3];
      a = au.v;
    }
#pragma unroll
    for (int nt = 0; nt < 4; ++nt) {
      bf16x8 bf = *(const bf16x8*)(Bb + (p0 + nt*16 + lr) * BSTR + ks + quad*8);
      acc[nt] = __builtin_amdgcn_mfma_f32_16x16x32_bf16(a, bf, acc[nt], 0, 0, 0);
    }
  }
  if constexpr (REM2) {
#pragma unroll
    for (int rr = 0; rr < 4; ++rr) {
      int o = o0 + quad*4 + rr;
      unsigned int wu = *(const unsigned int*)(W + (long)o * KW + KMAIN);
      float w0 = bf2f(wu & 0xffff), w1 = bf2f(wu >> 16);
#pragma unroll
      for (int nt = 0; nt < 4; ++nt) {
        long p = p0 + nt*16 + lr;
        unsigned int bu = *(const unsigned int*)(Bb + p * BSTR + KMAIN);
        acc[nt][rr] += w0 * bf2f(bu & 0xffff) + w1 * bf2f(bu >> 16);
      }
    }
  }
  if constexpr (EPI == 0) {
#pragma unroll
    for (int nt = 0; nt < 4; ++nt) {
      long p = p0 + nt*16 + lr;
      unsigned short v0 = f2bf(fmaxf(acc[nt][0], 0.f));
      unsigned short v1 = f2bf(fmaxf(acc[nt][1], 0.f));
      unsigned short v2 = f2bf(fmaxf(acc[nt][2], 0.f));
      unsigned short v3 = f2bf(fmaxf(acc[nt][3], 0.f));
      unsigned short* op = Out + p * OSTR + OOFF + o0 + quad*4;
      if constexpr (((OOFF * 2) % 8) == 0) {
        union { unsigned long long u; unsigned short s[4]; } pk;
        pk.s[0] = v0; pk.s[1] = v1; pk.s[2] = v2; pk.s[3] = v3;
        *(unsigned long long*)op = pk.u;
      } else {
        *(unsigned int*)op       = (unsigned int)v0 | ((unsigned int)v1 << 16);
        *(unsigned int*)(op + 2) = (unsigned int)v2 | ((unsigned int)v3 << 16);
      }
    }
  } else {  // EPI == 2
#pragma unroll
    for (int rr = 0; rr < 4; ++rr) {
      float v = fmaxf(fmaxf(acc[0][rr], acc[1][rr]), fmaxf(acc[2][rr], acc[3][rr]));
      v = fmaxf(v, 0.f);
      v = fmaxf(v, __shfl_xor(v, 1, 64));
      v = fmaxf(v, __shfl_xor(v, 2, 64));
      v = fmaxf(v, __shfl_xor(v, 4, 64));
      v = fmaxf(v, __shfl_xor(v, 8, 64));
      if (lr == 0) {
        int bb2 = (int)(blockIdx.x >> 2);   // blockIdx.x = br
        atomicMax(&outmax[bb2 * FF + o0 + quad*4 + rr], __float_as_uint(v));
      }
    }
  }
}

// ---------------- K7: output convert (dtype-adaptive) ----------------
__global__ __launch_bounds__(256) void k_out(
    const unsigned int* __restrict__ outmax, const int* __restrict__ flag,
    void* __restrict__ out) {
  int t = blockIdx.x * 256 + threadIdx.x;
  float v = __uint_as_float(outmax[t]);
  if (flag[0]) ((unsigned short*)out)[t] = f2bf(v);
  else         ((float*)out)[t] = v;
}

// ---------------- host ----------------
extern "C" void kernel_launch(void* const* d_in, const int* in_sizes, int n_in,
                              void* d_out, int out_size, void* d_ws, size_t ws_size,
                              hipStream_t stream) {
  const void* x    = d_in[0];
  const void* node = d_in[2];
  const void* fpW0 = d_in[4];  const void* fpb0 = d_in[5];
  const void* fpW1 = d_in[6];  const void* fpb1 = d_in[7];
  const void* fpW2 = d_in[8];  const void* fpb2 = d_in[9];
  const void* fpW3 = d_in[10]; const void* fpb3 = d_in[11];
  const void* gpW0 = d_in[12]; const void* gpb0 = d_in[13];
  const void* gpW1 = d_in[14]; const void* gpb1 = d_in[15];
  const void* gpW2 = d_in[16]; const void* gpb2 = d_in[17];
  const void* gpW3 = d_in[18]; const void* gpb3 = d_in[19];

  // workspace layout (~4.5 MB total; zeroed region first)
  char* ws = (char*)d_ws;
  int*            flag    = (int*)(ws + 0);              //    256 (4 used)
  float*          csum    = (float*)(ws + 256);          //   3072
  unsigned int*   outmax  = (unsigned int*)(ws + 3328);  //   8192
  unsigned int*   pooled  = (unsigned int*)(ws + 11520); // 524288
  // ---- end of memset region (535808 B) ----
  int*            idx     = (int*)(ws + 535808);         // 196608
  int*            blkcnt  = (int*)(ws + 732416);         //  16384
  int*            blkoff  = (int*)(ws + 748800);         //  16384
  int*            off     = (int*)(ws + 765184);         //   1024
  float*          noderot = (float*)(ws + 766208);       //   8192
  int*            rowflag = (int*)(ws + 774400);         //   1024
  int*            sorted  = (int*)(ws + 775424);         // 196608
  float*          feat0   = (float*)(ws + 972032);       //   8192
  unsigned short* AG      = (unsigned short*)(ws + 980224);   // 1327104
  unsigned short* Hg1     = (unsigned short*)(ws + 2307328);  // 524288
  unsigned short* Hg2     = (unsigned short*)(ws + 2831616);  // 524288
  unsigned short* Wb      = (unsigned short*)(ws + 3355904);  // 1175040

  hipMemsetAsync(ws, 0, 535808, stream);

  k_detect<<<1, 256, 0, stream>>>((const unsigned short*)x, flag);
  WPtrs wp; wp.p[0]=fpW1; wp.p[1]=fpW2; wp.p[2]=fpW3; wp.p[3]=gpW0;
  wp.p[4]=gpW1; wp.p[5]=gpW2; wp.p[6]=gpW3;
  k_cvt<<<2295, 256, 0, stream>>>(wp, flag, Wb);

  k_assign<<<64, 256, 0, stream>>>(x, node, flag, idx, csum, blkcnt);
  k_means<<<1, 256, 0, stream>>>(csum, blkcnt, noderot, rowflag, off, blkoff);
  k_scatter<<<64, 256, 0, stream>>>(idx, blkoff, sorted);
  k_fused<<<dim3(192, 16), 256, 0, stream>>>(x, sorted, idx, noderot, flag,
                                             fpW0, fpb0, Wb, fpb1, fpb2, fpb3,
                                             pooled, feat0);
  k_finalize<<<512, 256, 0, stream>>>(pooled, feat0, rowflag, noderot, AG);

  // gp layers over 1024 columns (br*64+m); weights from canonical bf16 Wb
  const unsigned short* gW0 = Wb + 28928;
  const unsigned short* gW1 = Wb + 62208;
  const unsigned short* gW2 = Wb + 127744;
  const unsigned short* gW3 = Wb + 258816;
  k_gemm<130, 128, true, 648, 256, 0, 0><<<dim3(16, 4), 256, 0, stream>>>(gW0, gpb0, flag, AG, Hg1, nullptr);
  k_gemm<256, 256, false, 256, 256, 0, 0><<<dim3(16, 4), 256, 0, stream>>>(gW1, gpb1, flag, Hg1, Hg2, nullptr);
  k_gemm<256, 256, false, 256, 648, 130, 0><<<dim3(16, 8), 256, 0, stream>>>(gW2, gpb2, flag, Hg2, AG, nullptr);
  k_gemm<642, 640, true, 648, 0, 0, 2><<<dim3(16, 8), 256, 0, stream>>>(gW3, gpb3, flag, AG, nullptr, outmax);

  k_out<<<8, 256, 0, stream>>>(outmax, flag, d_out);
}